// Round 7
// baseline (440.677 us; speedup 1.0000x reference)
//
#include <hip/hip_runtime.h>
#include <stdint.h>

// Problem constants (B=8,T=8192,H=512,E=4,R=16)
#define NTOK 65536
#define HD   512
#define EXP  4
#define RK   16

typedef __attribute__((ext_vector_type(8)))  short short8;
typedef __attribute__((ext_vector_type(4)))  float f32x4;
typedef __attribute__((ext_vector_type(16))) float f32x16;

__device__ __forceinline__ unsigned short f2bf(float f) {
  union { float f; unsigned int u; } c; c.f = f;
  return (unsigned short)((c.u + 0x7fffu + ((c.u >> 16) & 1u)) >> 16);
}

__device__ __forceinline__ void gl_lds16(const void* g, void* l) {
  __builtin_amdgcn_global_load_lds((const __attribute__((address_space(1))) void*)g,
                                   (__attribute__((address_space(3))) void*)l, 16, 0, 0);
}

// ---------------- merged prep: w1b + laT + Mt + gwp (one launch) ----------------
// blocks [0,1024):     fc1_w fp32->bf16
// blocks [1024,1152):  laT[e][r][h] = bf16(lora_A[e][h][r])
// blocks [1152,9344):  Mt[d][e*16+r] = sum_o lora_B[e,r,o]*fc2_w[e,d,o] (wave/output)
// blocks [9344,9352):  gwp: gate weights pre-packed in 32x32x16 B-frag layout:
//   gwp[s*512 + lane*8 + j] = W[col=lane&31][k = s*16 + (lane>>5)*8 + j],
//   W rows 0-3 = gate_w, row 4 = thr_w, rows 5-31 = 0.  (s = K-phase 0..31)
__global__ void prep_all(const float* __restrict__ fc1w, unsigned short* __restrict__ w1b,
                         const float* __restrict__ la, unsigned short* __restrict__ laT,
                         const float* __restrict__ loraB, const float* __restrict__ fc2,
                         unsigned short* __restrict__ Mt,
                         const float* __restrict__ gw, const float* __restrict__ tw,
                         unsigned short* __restrict__ gwp) {
  const int bid = blockIdx.x, tid = threadIdx.x;
  if (bid < 1024) {
    int i = bid * 256 + tid;
    float4 v = ((const float4*)fc1w)[i];
    ushort4 u;
    u.x = f2bf(v.x); u.y = f2bf(v.y); u.z = f2bf(v.z); u.w = f2bf(v.w);
    ((ushort4*)w1b)[i] = u;
  } else if (bid < 1152) {
    int idx = (bid - 1024) * 256 + tid;       // 0..32767
    int h = idx & (HD - 1);
    int er = idx >> 9;                        // e*16+r
    int e = er >> 4, r = er & 15;
    laT[(size_t)er * HD + h] = f2bf(la[((size_t)e * HD + h) * RK + r]);
  } else if (bid < 9344) {
    const int wid = (bid - 1152) * 4 + (tid >> 6);  // 0..32767
    const int lane = tid & 63;
    const int d = wid & (HD - 1);
    const int er = wid >> 9;
    const int e = er >> 4, r = er & 15;
    const float4* B = (const float4*)(loraB + ((size_t)e * RK + r) * HD);
    const float4* F = (const float4*)(fc2 + ((size_t)e * HD + d) * HD);
    const float4 b0 = B[lane * 2], b1 = B[lane * 2 + 1];
    const float4 f0 = F[lane * 2], f1 = F[lane * 2 + 1];
    float s = b0.x * f0.x + b0.y * f0.y + b0.z * f0.z + b0.w * f0.w
            + b1.x * f1.x + b1.y * f1.y + b1.z * f1.z + b1.w * f1.w;
#pragma unroll
    for (int off = 32; off > 0; off >>= 1) s += __shfl_xor(s, off, 64);
    if (lane == 0) Mt[d * 64 + er] = f2bf(s);
  } else {
    const int pair = (bid - 9344) * 256 + tid;  // 0..2047 = (s,lane)
    const int s = pair >> 6, ln = pair & 63;
    const int col = ln & 31;
    const int kb = s * 16 + (ln >> 5) * 8;
    union { short8 v; unsigned short u[8]; } o;
#pragma unroll
    for (int jj = 0; jj < 8; jj++) {
      float v = 0.f;
      if (col < 4) v = gw[col * HD + kb + jj];
      else if (col == 4) v = tw[kb + jj];
      o.u[jj] = f2bf(v);
    }
    *(short8*)(gwp + (size_t)pair * 8) = o.v;
  }
}

// ---------------- fused convert + gate + fc1 + relu + lora_A ----------------
// Round-7: reads x f32 DIRECTLY (no xbp round-trip, convgate kernel eliminated).
// A-path: reg-staged (4x global_load_dwordx4 f32 per tile, in-flight f2bf,
// 2x ds_write_b128 to the proven swizzled layout). B-path: gl_lds unchanged.
// Ring-3 LDS; B staged 2 tiles ahead (gl_lds), A-regs 1 tile ahead.
// vmcnt ledger (A loads + B gl_lds both count, issue order known):
//   tile t issues: phase0 A(t+1)x4 -> phase1 B(t+2)x2.
//   boundary vmcnt(2) leaves newest 2 (B(t+2)) -> A(t+1),B(t+1) resident;
//   then cvt+ds_write A(t+1), lgkm(0), barrier. Tail: t=14 vmcnt(0).
// Gating fused (eh==0 blocks): gwp staged to LDS once; every wave does +1
// 32x32x16 MFMA per phase on its own 32 tokens (A-frag row block wave&3);
// epilogue: LDS transpose -> softmax/threshold -> gates[n][4] (float4).
// lw has NO atomics/memset: per-hq planes lw[hq][N][64], plain stores.
__launch_bounds__(512, 2)
__global__ void fc1_lora(const float* __restrict__ x,
                         const unsigned short* __restrict__ w1b,
                         const unsigned short* __restrict__ laT,
                         const unsigned short* __restrict__ gwp,
                         float* __restrict__ lw,
                         float* __restrict__ gates) {
  __shared__ __align__(16) char smem[135168];  // ring 3x32KB + gwl 32KB; epi hsm 256x264x2
  const int bid = blockIdx.x;           // 2048 blocks
  const int c = bid & 7;                // XCD
  const int j = bid >> 3;               // 0..255 within XCD
  const int eh = j & 7;
  const int e = eh >> 1, hq = eh & 1;   // expert, h-half (256 h each)
  const int ntile = c * 32 + (j >> 3);
  const int n0 = ntile * 256;
  const int tid = threadIdx.x;
  const int wave = tid >> 6, lane = tid & 63;
  const int l16 = lane & 15, quad = lane >> 4;
  const int l32 = lane & 31, half = lane >> 5;
  const int wr = wave >> 2, wc = wave & 3;   // 2M x 4N wave grid (each 128x64 out)
  const bool gateB = (eh == 0);

  const unsigned short* wg = w1b + ((size_t)e * HD + (size_t)hq * 256) * HD;

  // staging sources: slot S = tid + 512*i; sr=S>>3, g8=(S&7)^(sr&7),
  // row=sr*2+(g8>>2), granule=g8&3. A from f32 x (reg-staged), B pre-swizzled gl_lds.
  const float4* asrc[2];
  const unsigned short* wsrc[2];
#pragma unroll
  for (int i = 0; i < 2; i++) {
    const int sl = tid + 512 * i;
    const int sr = sl >> 3, g8 = (sl & 7) ^ (sr & 7);
    const int row = sr * 2 + (g8 >> 2), g = g8 & 3;
    asrc[i] = (const float4*)(x + (size_t)(n0 + row) * HD + g * 8);
    wsrc[i] = wg + (size_t)row * HD + g * 8;
  }
  const int wbase = wave * 1024;

  // loop-invariant LDS read byte offsets: [phase][frag]; needed granule = p*2+half
  int axo[2][4], bxo[2][2], axg[2];
#pragma unroll
  for (int p = 0; p < 2; p++) {
#pragma unroll
    for (int mb = 0; mb < 4; mb++) {
      const int rowa = wr * 128 + mb * 32 + l32;
      const int sr = rowa >> 1, g8 = (rowa & 1) * 4 + p * 2 + half;
      axo[p][mb] = (sr * 8 + (g8 ^ (sr & 7))) * 16;
    }
#pragma unroll
    for (int nb = 0; nb < 2; nb++) {
      const int rowb = wc * 64 + nb * 32 + l32;
      const int sr = rowb >> 1, g8 = (rowb & 1) * 4 + p * 2 + half;
      bxo[p][nb] = (sr * 8 + (g8 ^ (sr & 7))) * 16;
    }
    const int rowg = wave * 32 + l32;   // gate token rows for this wave
    const int srg = rowg >> 1, g8g = (rowg & 1) * 4 + p * 2 + half;
    axg[p] = (srg * 8 + (g8g ^ (srg & 7))) * 16;
  }

  f32x16 acc[4][2];
#pragma unroll
  for (int mb = 0; mb < 4; mb++)
#pragma unroll
    for (int nb = 0; nb < 2; nb++)
#pragma unroll
      for (int r = 0; r < 16; r++) acc[mb][nb][r] = 0.f;
  f32x16 gacc;
#pragma unroll
  for (int r = 0; r < 16; r++) gacc[r] = 0.f;

  char* gwl = smem + 98304;   // 32 KB gate-weight frags
  float4 abuf[4];

  // ---- prologue: [gwp x4 (eh0)], A0 x4 (regs), B0 x2, B1 x2 ----
  if (gateB) {
#pragma unroll
    for (int i = 0; i < 4; i++)
      gl_lds16((const char*)gwp + tid * 16 + i * 8192, gwl + wbase + i * 8192);
  }
  abuf[0] = asrc[0][0]; abuf[1] = asrc[0][1];
  abuf[2] = asrc[1][0]; abuf[3] = asrc[1][1];
#pragma unroll
  for (int i = 0; i < 2; i++) gl_lds16(wsrc[i], smem + 16384 + wbase + 8192 * i);
#pragma unroll
  for (int i = 0; i < 2; i++) gl_lds16(wsrc[i] + 32, smem + 32768 + 16384 + wbase + 8192 * i);
  asm volatile("s_waitcnt vmcnt(2)" ::: "memory");   // all but B1 done (gwp,A0,B0)
  {
    union { short8 v; unsigned short u[8]; } wa, wb;
    wa.u[0] = f2bf(abuf[0].x); wa.u[1] = f2bf(abuf[0].y); wa.u[2] = f2bf(abuf[0].z); wa.u[3] = f2bf(abuf[0].w);
    wa.u[4] = f2bf(abuf[1].x); wa.u[5] = f2bf(abuf[1].y); wa.u[6] = f2bf(abuf[1].z); wa.u[7] = f2bf(abuf[1].w);
    wb.u[0] = f2bf(abuf[2].x); wb.u[1] = f2bf(abuf[2].y); wb.u[2] = f2bf(abuf[2].z); wb.u[3] = f2bf(abuf[2].w);
    wb.u[4] = f2bf(abuf[3].x); wb.u[5] = f2bf(abuf[3].y); wb.u[6] = f2bf(abuf[3].z); wb.u[7] = f2bf(abuf[3].w);
    *(short8*)(smem + tid * 16) = wa.v;
    *(short8*)(smem + tid * 16 + 8192) = wb.v;
  }
  asm volatile("s_waitcnt lgkmcnt(0)" ::: "memory");
  __builtin_amdgcn_s_barrier();
  __builtin_amdgcn_sched_barrier(0);

  // ---- main loop: 16 K-tiles of 32; 2 phases/tile ----
#pragma unroll
  for (int t = 0; t < 16; t++) {
    char* Ab = smem + (t % 3) * 32768;
    char* Bb = Ab + 16384;
#pragma unroll
    for (int p = 0; p < 2; p++) {
      short8 af[4], bf[2], gaf, gwb;
#pragma unroll
      for (int mb = 0; mb < 4; mb++) af[mb] = *(const short8*)(Ab + axo[p][mb]);
#pragma unroll
      for (int nb = 0; nb < 2; nb++) bf[nb] = *(const short8*)(Bb + bxo[p][nb]);
      if (gateB) {
        gaf = *(const short8*)(Ab + axg[p]);
        gwb = *(const short8*)(gwl + (t * 2 + p) * 1024 + lane * 16);
      }
      if (p == 0 && t < 15) {            // issue A(t+1) f32 loads -> regs
        const int a4 = (t + 1) * 8;
        abuf[0] = asrc[0][a4]; abuf[1] = asrc[0][a4 + 1];
        abuf[2] = asrc[1][a4]; abuf[3] = asrc[1][a4 + 1];
      }
      if (p == 1 && t < 14) {            // issue B(t+2) gl_lds
        const int kos = (t + 2) * 32;
        char* Bs = smem + ((t + 2) % 3) * 32768 + 16384;
        gl_lds16(wsrc[0] + kos, Bs + wbase);
        gl_lds16(wsrc[1] + kos, Bs + wbase + 8192);
      }
      __builtin_amdgcn_s_barrier();
      asm volatile("s_waitcnt lgkmcnt(0)" ::: "memory");
      __builtin_amdgcn_sched_barrier(0);
      __builtin_amdgcn_s_setprio(1);
#pragma unroll
      for (int mb = 0; mb < 4; mb++)
#pragma unroll
        for (int nb = 0; nb < 2; nb++)
          acc[mb][nb] = __builtin_amdgcn_mfma_f32_32x32x16_bf16(af[mb], bf[nb], acc[mb][nb], 0, 0, 0);
      if (gateB)
        gacc = __builtin_amdgcn_mfma_f32_32x32x16_bf16(gaf, gwb, gacc, 0, 0, 0);
      __builtin_amdgcn_s_setprio(0);
      if (p == 0) {
        __builtin_amdgcn_s_barrier();
      } else {
        // boundary: A(t+1)+B(t+1) must be resident; newest-2 = B(t+2)
        if (t < 14)       asm volatile("s_waitcnt vmcnt(2)" ::: "memory");
        else if (t == 14) asm volatile("s_waitcnt vmcnt(0)" ::: "memory");
        if (t < 15) {     // cvt + ds_write A(t+1) into slot (t+1)%3
          char* Aw = smem + ((t + 1) % 3) * 32768;
          union { short8 v; unsigned short u[8]; } wa, wb2;
          wa.u[0] = f2bf(abuf[0].x); wa.u[1] = f2bf(abuf[0].y); wa.u[2] = f2bf(abuf[0].z); wa.u[3] = f2bf(abuf[0].w);
          wa.u[4] = f2bf(abuf[1].x); wa.u[5] = f2bf(abuf[1].y); wa.u[6] = f2bf(abuf[1].z); wa.u[7] = f2bf(abuf[1].w);
          wb2.u[0] = f2bf(abuf[2].x); wb2.u[1] = f2bf(abuf[2].y); wb2.u[2] = f2bf(abuf[2].z); wb2.u[3] = f2bf(abuf[2].w);
          wb2.u[4] = f2bf(abuf[3].x); wb2.u[5] = f2bf(abuf[3].y); wb2.u[6] = f2bf(abuf[3].z); wb2.u[7] = f2bf(abuf[3].w);
          *(short8*)(Aw + tid * 16) = wa.v;
          *(short8*)(Aw + tid * 16 + 8192) = wb2.v;
        }
        asm volatile("s_waitcnt lgkmcnt(0)" ::: "memory");
        __builtin_amdgcn_s_barrier();
      }
      __builtin_amdgcn_sched_barrier(0);
    }
  }

  // ---- gate epilogue (eh==0): transpose gacc via LDS, softmax+thr, store ----
  if (gateB) {
    float* gsm = (float*)smem;             // [256][8] f32 (ring slot 0 is dead)
    if (l32 < 5) {
#pragma unroll
      for (int r = 0; r < 16; r++) {
        const int row32 = 4 * half + (r & 3) + 8 * (r >> 2);
        gsm[(wave * 32 + row32) * 8 + l32] = gacc[r];
      }
    }
    __syncthreads();
    if (tid < 256) {
      const float s0 = gsm[tid * 8 + 0], s1 = gsm[tid * 8 + 1];
      const float s2 = gsm[tid * 8 + 2], s3 = gsm[tid * 8 + 3];
      const float s4 = gsm[tid * 8 + 4];
      float m = fmaxf(fmaxf(s0, s1), fmaxf(s2, s3));
      float e0 = expf(s0 - m), e1 = expf(s1 - m), e2 = expf(s2 - m), e3 = expf(s3 - m);
      float inv = 1.f / (e0 + e1 + e2 + e3);
      float thr = 0.25f / (1.f + expf(-s4));
      float a0 = e0 * inv - thr, a1 = e1 * inv - thr, a2 = e2 * inv - thr, a3 = e3 * inv - thr;
      float w0 = a0 > 0.f ? a0 : 0.f, w1 = a1 > 0.f ? a1 : 0.f;
      float w2 = a2 > 0.f ? a2 : 0.f, w3 = a3 > 0.f ? a3 : 0.f;
      float wsum = w0 + w1 + w2 + w3;
      wsum = (wsum == 0.f) ? 1.f : wsum;
      float4 gv; gv.x = w0 / wsum; gv.y = w1 / wsum; gv.z = w2 / wsum; gv.w = w3 / wsum;
      *(float4*)(gates + (size_t)(n0 + tid) * 4) = gv;
    }
    __syncthreads();
  }

  // ---- stage 2: relu -> bf16 hidden to block-shared LDS [256 tok][264 shorts] ----
  unsigned short* hsm = (unsigned short*)smem;
#pragma unroll
  for (int mb = 0; mb < 4; mb++)
#pragma unroll
    for (int nb = 0; nb < 2; nb++) {
      const int colh = wc * 64 + nb * 32 + l32;
#pragma unroll
      for (int r = 0; r < 16; r++) {
        const int tok = wr * 128 + mb * 32 + 4 * half + (r & 3) + 8 * (r >> 2);
        float v = acc[mb][nb][r];
        v = v > 0.f ? v : 0.f;
        hsm[tok * 264 + colh] = f2bf(v);
      }
    }
  __syncthreads();

  // ---- lo[tok][r] over this block's 256 h; plain stores to lw[hq] plane ----
  const unsigned short* laTe = laT + (size_t)(e * 16 + l16) * HD + hq * 256;
  f32x4 lo[2];
#pragma unroll
  for (int mf = 0; mf < 2; mf++)
#pragma unroll
    for (int i = 0; i < 4; i++) lo[mf][i] = 0.f;
#pragma unroll
  for (int k2 = 0; k2 < 8; k2++) {
    const short8 b2 = *(const short8*)(laTe + k2 * 32 + quad * 8);
#pragma unroll
    for (int mf = 0; mf < 2; mf++) {
      const int tok = wave * 32 + mf * 16 + l16;
      const short8 a2 = *(const short8*)(hsm + tok * 264 + k2 * 32 + quad * 8);
      lo[mf] = __builtin_amdgcn_mfma_f32_16x16x32_bf16(a2, b2, lo[mf], 0, 0, 0);
    }
  }
  float* lwh = lw + (size_t)hq * NTOK * 64;
#pragma unroll
  for (int mf = 0; mf < 2; mf++)
#pragma unroll
    for (int i = 0; i < 4; i++)
      lwh[(size_t)(n0 + wave * 32 + mf * 16 + quad * 4 + i) * 64 + e * 16 + l16] = lo[mf][i];
}

// ---------------- combine: out[n][d] = sum_k ((lw0+lw1)[n][k]*gate[n][k/16]) * Mt[d][k] --------
// Mt staged into LDS (XOR-swizzled granules, conflict-free); transpose epilogue
// for float4 stores (round 4).
__launch_bounds__(256, 2)
__global__ void combine_k(const float* __restrict__ lw, const float* __restrict__ gates,
                          const unsigned short* __restrict__ Mt, float* __restrict__ out) {
  __shared__ __align__(16) char smem[65536];
  const int n0 = blockIdx.x * 64;
  const int tid = threadIdx.x;
  const int wave = tid >> 6, lane = tid & 63, quad = lane >> 4, l16 = lane & 15;
#pragma unroll
  for (int i = 0; i < 16; i++) {
    const int slot = tid + 256 * i;          // 0..4095
    const int row = slot >> 3;
    const int g = (slot & 7) ^ (row & 7);
    *(uint4*)(smem + slot * 16) = *(const uint4*)(Mt + row * 64 + g * 8);
  }
  __syncthreads();
  f32x4 acc[4][8];
#pragma unroll
  for (int a = 0; a < 4; a++)
#pragma unroll
    for (int b = 0; b < 8; b++)
#pragma unroll
      for (int i = 0; i < 4; i++) acc[a][b][i] = 0.f;
#pragma unroll
  for (int ks = 0; ks < 2; ks++) {
    short8 af[4], bfr[8];
#pragma unroll
    for (int mf = 0; mf < 4; mf++) {
      const int n = n0 + mf * 16 + l16;
      const float* lr0 = lw + (size_t)n * 64 + ks * 32 + quad * 8;
      const float* lr1 = lr0 + (size_t)NTOK * 64;
      float4 a0 = *(const float4*)lr0,       a1 = *(const float4*)(lr0 + 4);
      float4 b0 = *(const float4*)lr1,       b1 = *(const float4*)(lr1 + 4);
      float4 u0, u1;
      u0.x = a0.x + b0.x; u0.y = a0.y + b0.y; u0.z = a0.z + b0.z; u0.w = a0.w + b0.w;
      u1.x = a1.x + b1.x; u1.y = a1.y + b1.y; u1.z = a1.z + b1.z; u1.w = a1.w + b1.w;
      const float g = gates[(size_t)n * 4 + ((ks * 32 + quad * 8) >> 4)];
      union { short8 v; unsigned short s[8]; } a;
      a.s[0] = f2bf(u0.x * g); a.s[1] = f2bf(u0.y * g);
      a.s[2] = f2bf(u0.z * g); a.s[3] = f2bf(u0.w * g);
      a.s[4] = f2bf(u1.x * g); a.s[5] = f2bf(u1.y * g);
      a.s[6] = f2bf(u1.z * g); a.s[7] = f2bf(u1.w * g);
      af[mf] = a.v;
    }
#pragma unroll
    for (int nf = 0; nf < 8; nf++) {
      const int row = wave * 128 + nf * 16 + l16;
      const int slot = row * 8 + ((ks * 4 + quad) ^ (row & 7));
      bfr[nf] = *(const short8*)(smem + slot * 16);
    }
#pragma unroll
    for (int mf = 0; mf < 4; mf++)
#pragma unroll
      for (int nf = 0; nf < 8; nf++)
        acc[mf][nf] = __builtin_amdgcn_mfma_f32_16x16x32_bf16(af[mf], bfr[nf], acc[mf][nf], 0, 0, 0);
  }
  __syncthreads();
  float* scr = (float*)smem + wave * 320;   // [16][20] f32
#pragma unroll
  for (int mf = 0; mf < 4; mf++)
#pragma unroll
    for (int nf = 0; nf < 8; nf++) {
#pragma unroll
      for (int i = 0; i < 4; i++) scr[(quad * 4 + i) * 20 + l16] = acc[mf][nf][i];
      float4 v = *(const float4*)(scr + l16 * 20 + quad * 4);
      *(float4*)(out + (size_t)(n0 + mf * 16 + l16) * HD + wave * 128 + nf * 16 + quad * 4) = v;
    }
}

// ---------------- launch ----------------
extern "C" void kernel_launch(void* const* d_in, const int* in_sizes, int n_in,
                              void* d_out, int out_size, void* d_ws, size_t ws_size,
                              hipStream_t stream) {
  const float* x      = (const float*)d_in[0];
  const float* gate_w = (const float*)d_in[1];
  const float* thr_w  = (const float*)d_in[2];
  const float* fc1_w  = (const float*)d_in[3];
  const float* lora_A = (const float*)d_in[4];
  const float* lora_B = (const float*)d_in[5];
  const float* fc2_w  = (const float*)d_in[6];
  float* out = (float*)d_out;
  char* ws = (char*)d_ws;

  float*          lwp = (float*)(ws);                            // 33554432 B (2 planes)
  unsigned short* w1b = (unsigned short*)(ws + 33554432);        //  2097152 B
  unsigned short* Mt  = (unsigned short*)(ws + 35651584);        //    65536 B
  unsigned short* laT = (unsigned short*)(ws + 35717120);        //    65536 B
  unsigned short* gwp = (unsigned short*)(ws + 35782656);        //    32768 B
  float*          gts = (float*)(ws + 35815424);                 //  1048576 B

  prep_all<<<9352, 256, 0, stream>>>(fc1_w, w1b, lora_A, laT, lora_B, fc2_w, Mt,
                                     gate_w, thr_w, gwp);
  fc1_lora<<<2048, 512, 0, stream>>>(x, w1b, laT, gwp, lwp, gts);
  combine_k<<<NTOK / 64, 256, 0, stream>>>(lwp, gts, Mt, out);
}